// Round 6
// baseline (331.027 us; speedup 1.0000x reference)
//
#include <hip/hip_runtime.h>

typedef short v8s __attribute__((ext_vector_type(8)));
typedef float v4f __attribute__((ext_vector_type(4)));

__device__ inline unsigned short f2bf(float f) {
    unsigned u = __float_as_uint(f);
    u += 0x7fff + ((u >> 16) & 1);
    return (unsigned short)(u >> 16);
}
__device__ inline float bf2f(unsigned short h) {
    return __uint_as_float(((unsigned)h) << 16);
}

// async global->LDS, 16B per lane. LDS dest is wave-uniform base; HW adds lane*16.
__device__ inline void gload_lds16(const void* g, void* l) {
    __builtin_amdgcn_global_load_lds(
        (const __attribute__((address_space(1))) unsigned*)(unsigned long long)(uintptr_t)g,
        (__attribute__((address_space(3))) unsigned*)(unsigned)(uintptr_t)l, 16, 0, 0);
}

// ---------------------------------------------------------------------------
// transpose (LDS-staged, coalesced both ways): NCHW fp32 input+guidance ->
// X0 [b][hw][128c] rot-swizzled bf16 (256B/px) and inN [b][hw][64c] bf16 (rot&127).
__global__ void transpose_kernel(const float* __restrict__ input, const float* __restrict__ guidance,
                                 char* __restrict__ X0, char* __restrict__ inN)
{
    __shared__ unsigned lds[64 * 66];
    const int tid = threadIdx.x;
    const int b = blockIdx.y;
    const size_t hw0 = (size_t)blockIdx.x * 64;

    for (int it = 0; it < 16; ++it) {
        int p  = it * 4 + (tid >> 6);     // channel-pair 0..63
        int px = tid & 63;
        size_t hw = hw0 + px;
        int c0 = 2 * p;
        float f0 = (c0 < 64) ? input[((size_t)(b * 64 + c0) << 16) + hw]
                             : guidance[((size_t)(b * 64 + c0 - 64) << 16) + hw];
        float f1 = (c0 + 1 < 64) ? input[((size_t)(b * 64 + c0 + 1) << 16) + hw]
                                 : guidance[((size_t)(b * 64 + c0 - 63) << 16) + hw];
        lds[px * 66 + p] = (unsigned)f2bf(f0) | ((unsigned)f2bf(f1) << 16);
    }
    __syncthreads();

    char* xbase = X0 + (((size_t)b * 65536 + hw0) << 8);
    for (int it = 0; it < 4; ++it) {
        int chunk = it * 256 + tid;       // 1024 chunks of 16B
        int px  = chunk >> 4;
        int ofs = (chunk & 15) << 4;
        int u   = (ofs - ((px & 7) << 4)) & 255;
        const unsigned* s = &lds[px * 66 + (u >> 2)];
        *(uint4*)(xbase + px * 256 + ofs) = make_uint4(s[0], s[1], s[2], s[3]);
    }
    char* ibase = inN + (((size_t)b * 65536 + hw0) << 7);
    for (int it = 0; it < 2; ++it) {
        int chunk = it * 256 + tid;       // 512 chunks of 16B
        int px  = chunk >> 3;
        int ofs = (chunk & 7) << 4;
        int u   = (ofs - ((px & 7) << 4)) & 127;
        const unsigned* s = &lds[px * 66 + (u >> 2)];
        *(uint4*)(ibase + px * 128 + ofs) = make_uint4(s[0], s[1], s[2], s[3]);
    }
}

// ---------------------------------------------------------------------------
// merged weight prepack.
// conv1 sets: [64][128][3][3] fp32 -> [tau][ick(4)][ng(4)][lane][8j]
// conv2:      [576][64][3][3] fp32 -> [tau][ick(2)][ng(36)][lane][8j], PERM oc=(n%64)*9+n/64
__global__ void prepack_all(const float* __restrict__ cw_w2, const float* __restrict__ cw_w1,
                            const float* __restrict__ dw_w1, char* __restrict__ Bp2,
                            char* __restrict__ Bp1, char* __restrict__ Bpdw)
{
    int bid = blockIdx.x;
    if (bid < 1296) {
        int t = bid * 256 + threadIdx.x;
        int jj = t & 7, lane = (t >> 3) & 63;
        int r2 = t >> 9;
        int ng = r2 % 36, r3 = r2 / 36;
        int ick = r3 & 1, tau = r3 >> 1;
        if (tau >= 9) return;
        int n  = ng * 16 + (lane & 15);
        int ic = ick * 32 + (lane >> 4) * 8 + jj;
        int oc = (n & 63) * 9 + (n >> 6);
        float v = cw_w2[(((size_t)oc * 64 + ic) * 3 + tau / 3) * 3 + tau % 3];
        *(unsigned short*)(Bp2 + (size_t)t * 2) = f2bf(v);
    } else {
        int s = bid - 1296;
        int set = (s >= 288);
        const float* src = set ? dw_w1 : cw_w1;
        char* dst = set ? Bpdw : Bp1;
        int t = (set ? s - 288 : s) * 256 + threadIdx.x;
        int jj = t & 7, lane = (t >> 3) & 63;
        int r2 = t >> 9;
        int ng = r2 & 3, r3 = r2 >> 2;
        int ick = r3 & 3, tau = r3 >> 2;
        if (tau >= 9) return;
        int n  = ng * 16 + (lane & 15);
        int ic = ick * 32 + (lane >> 4) * 8 + jj;
        float v = src[(((size_t)n * 128 + ic) * 3 + tau / 3) * 3 + tau % 3];
        *(unsigned short*)(dst + (size_t)t * 2) = f2bf(v);
    }
}

// ---------------------------------------------------------------------------
// conv1 fused (cw + dw sets), TWO output rows per block. 4 input planes staged;
// plane p serves row0 (ty=p, p<=2) and row1 (ty=p-1, p>=1). B fragment for row1
// at plane p == B for row0 at plane p-1 -> rolling register, halves B loads/row.
__global__ __launch_bounds__(256, 2) void conv1_mfma(
    const char* __restrict__ X0, const char* __restrict__ Bp1, const char* __restrict__ Bp2,
    const float* __restrict__ b1, const float* __restrict__ b2,
    char* __restrict__ t1, float* __restrict__ hsum)
{
    constexpr int PP = 66 * 256;
    __shared__ __align__(16) char As[4 * PP];      // 67584

    const int tid = threadIdx.x, lane = tid & 63, w = tid >> 6;
    const int m16 = lane & 15, q = lane >> 4;
    const int col0 = blockIdx.x * 64;
    const int row0 = blockIdx.y * 2;
    const int b    = blockIdx.z;

    const char* rowbase = X0 + ((size_t)b * 65536) * 256;
    for (int idx = tid; idx < 4 * 1056; idx += 256) {
        int plane = idx / 1056;
        int gr = row0 + plane - 1;
        if ((unsigned)gr < 256u) {
            int wb  = (idx - plane * 1056) * 16;
            int pxo = wb >> 8;
            int gpx = min(max(col0 - 1 + pxo, 0), 255);
            gload_lds16(rowbase + (((size_t)gr * 256 + gpx) << 8) + (wb & 255),
                        As + (idx & ~63) * 16);
        }
    }
    __syncthreads();
    if (col0 == 0 && tid < 64)
        *(uint4*)(As + (tid >> 4) * PP + (tid & 15) * 16) = make_uint4(0, 0, 0, 0);
    if (col0 == 192 && tid < 64)
        *(uint4*)(As + (tid >> 4) * PP + 65 * 256 + (tid & 15) * 16) = make_uint4(0, 0, 0, 0);
    __syncthreads();

    v4f acc[2][4][2];   // [row][mg][set]
#pragma unroll
    for (int rr = 0; rr < 2; ++rr)
#pragma unroll
        for (int mg = 0; mg < 4; ++mg) { acc[rr][mg][0] = (v4f)(0.f); acc[rr][mg][1] = (v4f)(0.f); }

    const int boff = (w << 10) + (lane << 4);
#pragma unroll
    for (int tx = 0; tx < 3; ++tx) {
#pragma unroll
        for (int ick = 0; ick < 4; ++ick) {
            v8s b0p, b1p;
#pragma unroll
            for (int p = 0; p < 4; ++p) {
                v8s b0c, b1c;
                if (p <= 2) {
                    const int kstep = (p * 3 + tx) * 4 + ick;
                    b0c = *(const v8s*)(Bp1 + (size_t)kstep * 4096 + boff);
                    b1c = *(const v8s*)(Bp2 + (size_t)kstep * 4096 + boff);
                }
                const int grp = row0 + p - 1;
                const bool pv = (unsigned)grp < 256u;
                const char* plane = As + p * PP;
                v8s af[4];
#pragma unroll
                for (int mg = 0; mg < 4; ++mg) {
                    int px  = col0 + mg * 16 + m16 + tx - 1;
                    int tpx = mg * 16 + m16 + tx;
                    int off = (ick * 64 + q * 16 + ((px & 7) << 4)) & 255;
                    af[mg] = *(const v8s*)(plane + tpx * 256 + off);
                }
                if (pv && p <= 2) {
#pragma unroll
                    for (int mg = 0; mg < 4; ++mg) {
                        acc[0][mg][0] = __builtin_amdgcn_mfma_f32_16x16x32_bf16(af[mg], b0c, acc[0][mg][0], 0, 0, 0);
                        acc[0][mg][1] = __builtin_amdgcn_mfma_f32_16x16x32_bf16(af[mg], b1c, acc[0][mg][1], 0, 0, 0);
                    }
                }
                if (pv && p >= 1) {
#pragma unroll
                    for (int mg = 0; mg < 4; ++mg) {
                        acc[1][mg][0] = __builtin_amdgcn_mfma_f32_16x16x32_bf16(af[mg], b0p, acc[1][mg][0], 0, 0, 0);
                        acc[1][mg][1] = __builtin_amdgcn_mfma_f32_16x16x32_bf16(af[mg], b1p, acc[1][mg][1], 0, 0, 0);
                    }
                }
                b0p = b0c; b1p = b1c;
            }
        }
    }

    const int oc = w * 16 + m16;
#pragma unroll
    for (int rr = 0; rr < 2; ++rr) {
        const int row = row0 + rr;
        {
            float bb = b1[oc];
            char* dst = t1 + (((size_t)(b * 256 + row)) << 8) * 128;
#pragma unroll
            for (int mg = 0; mg < 4; ++mg)
#pragma unroll
                for (int r = 0; r < 4; ++r) {
                    int px = col0 + mg * 16 + (q << 2) + r;
                    float v = fmaxf(acc[rr][mg][0][r] + bb, 0.f);
                    *(unsigned short*)(dst + (size_t)px * 128 + ((oc * 2 + ((px & 7) << 4)) & 127)) = f2bf(v);
                }
        }
        {
            float bb = b2[oc];
            float s = 0.f;
#pragma unroll
            for (int mg = 0; mg < 4; ++mg)
#pragma unroll
                for (int r = 0; r < 4; ++r) s += fmaxf(acc[rr][mg][1][r] + bb, 0.f);
            s += __shfl_xor(s, 16, 64);
            s += __shfl_xor(s, 32, 64);
            if (lane < 16) atomicAdd(&hsum[b * 64 + oc], s);
        }
    }
}

// ---------------------------------------------------------------------------
// fused GAP 1x1 conv + fragment prepack:
// dwp[b][kick(2)][owg(4)][lane][8j] = bf16( sum_k h[b][k]/65536 * w2[o*64+c][k] + b2[o*64+c] )
__global__ void dwfused_kernel(const float* __restrict__ hsum, const float* __restrict__ w2,
                               const float* __restrict__ b2, char* __restrict__ dwp)
{
    __shared__ float h[64];
    int t = blockIdx.x * 256 + threadIdx.x;   // 8192 total
    int b = t >> 12;
    if (threadIdx.x < 64) h[threadIdx.x] = hsum[b * 64 + threadIdx.x] * (1.f / 65536.f);
    __syncthreads();
    int jj = t & 7, lane = (t >> 3) & 63;
    int r = t >> 9;
    int owg = r & 3, kick = (r >> 2) & 1;
    int o = owg * 16 + (lane & 15);
    int c = kick * 32 + ((lane >> 4) << 3) + jj;
    int n = o * 64 + c;
    float a = 0.f;
#pragma unroll
    for (int k = 0; k < 64; ++k) a = fmaf(h[k], w2[(size_t)n * 64 + k], a);
    *(unsigned short*)(dwp + (size_t)t * 2) = f2bf(a + b2[n]);
}

// ---------------------------------------------------------------------------
// FUSED conv2 + guided-filter + 1x1 + BN-stat atomics. Barrier-free unrolled
// K-loop; B fragments direct global->VGPR from L2-hot Bp2.
__global__ __launch_bounds__(256, 2) void conv2yz_kernel(
    const char* __restrict__ t1, const char* __restrict__ inN,
    const char* __restrict__ Bp2, const char* __restrict__ dwp,
    const float* __restrict__ cw_b2, float* __restrict__ zout,
    float* __restrict__ s1g, float* __restrict__ s2g)
{
    constexpr int PPA = 66 * 128;    // 8448 plane bytes
    __shared__ __align__(16) char As[3 * PPA];   // 25344
    __shared__ __align__(16) char Pt[3 * PPA];   // 25344
    __shared__ __align__(16) char Ys[8192];
    __shared__ __align__(16) char Dw[8192];

    const int tid = threadIdx.x, lane = tid & 63, w = tid >> 6;
    const int m16 = lane & 15, q = lane >> 4;
    const int col0 = blockIdx.x * 64;
    const int row  = blockIdx.y;
    const int b    = blockIdx.z;
    const int c_lane = w * 16 + m16;

    for (int idx = tid; idx < 512; idx += 256)
        gload_lds16(dwp + (size_t)b * 8192 + idx * 16, Dw + (idx & ~63) * 16);
    const char* arow = t1  + ((size_t)b * 65536) * 128;
    const char* prow = inN + ((size_t)b * 65536) * 128;
    for (int idx = tid; idx < 3 * 528; idx += 256) {
        int plane = idx / 528;
        int gr = row + plane - 1;
        if ((unsigned)gr < 256u) {
            int wb  = (idx - plane * 528) * 16;
            int pxo = wb >> 7;
            int gpx = min(max(col0 - 1 + pxo, 0), 255);
            size_t goff = (((size_t)gr * 256 + gpx) << 7) + (wb & 127);
            gload_lds16(arow + goff, As + (idx & ~63) * 16);
            gload_lds16(prow + goff, Pt + (idx & ~63) * 16);
        }
    }
    __syncthreads();
    if (col0 == 0 && tid < 24) {
        *(uint4*)(As + (tid / 8) * PPA + (tid & 7) * 16) = make_uint4(0, 0, 0, 0);
        *(uint4*)(Pt + (tid / 8) * PPA + (tid & 7) * 16) = make_uint4(0, 0, 0, 0);
    }
    if (col0 == 192 && tid < 24) {
        *(uint4*)(As + (tid / 8) * PPA + 65 * 128 + (tid & 7) * 16) = make_uint4(0, 0, 0, 0);
        *(uint4*)(Pt + (tid / 8) * PPA + 65 * 128 + (tid & 7) * 16) = make_uint4(0, 0, 0, 0);
    }
    __syncthreads();

    float bias9[9];
#pragma unroll
    for (int j = 0; j < 9; ++j) bias9[j] = cw_b2[c_lane * 9 + j];

    v4f acc[4][9];
#pragma unroll
    for (int mg = 0; mg < 4; ++mg)
#pragma unroll
        for (int ng = 0; ng < 9; ++ng) acc[mg][ng] = (v4f)(0.f);

    // ---- barrier-free conv2 K-loop (fully unrolled for load/MFMA pipelining) ----
    const int boff = (w << 10) + (lane << 4);
#pragma unroll 1
    for (int ty = 0; ty < 3; ++ty) {
        int gr = row + ty - 1;
        if ((unsigned)gr >= 256u) continue;
        const char* plane = As + ty * PPA;
#pragma unroll
        for (int tx = 0; tx < 3; ++tx) {
#pragma unroll
            for (int ick = 0; ick < 2; ++ick) {
                const int kstep = (ty * 3 + tx) * 2 + ick;
                const char* bbase = Bp2 + (size_t)kstep * 36864 + boff;
                v8s bf[9];
#pragma unroll
                for (int ng = 0; ng < 9; ++ng) bf[ng] = *(const v8s*)(bbase + (ng << 12));
                v8s af[4];
#pragma unroll
                for (int mg = 0; mg < 4; ++mg) {
                    int px  = col0 + mg * 16 + m16 + tx - 1;
                    int tpx = mg * 16 + m16 + tx;
                    int off = (ick * 64 + q * 16 + ((px & 7) << 4)) & 127;
                    af[mg] = *(const v8s*)(plane + tpx * 128 + off);
                }
#pragma unroll
                for (int ng = 0; ng < 9; ++ng)
#pragma unroll
                    for (int mg = 0; mg < 4; ++mg)
                        acc[mg][ng] = __builtin_amdgcn_mfma_f32_16x16x32_bf16(af[mg], bf[ng], acc[mg][ng], 0, 0, 0);
            }
        }
    }

    // ---- y[px][c_lane] in-register from patch ----
    float yv[4][4];
#pragma unroll
    for (int mg = 0; mg < 4; ++mg)
#pragma unroll
        for (int r = 0; r < 4; ++r) yv[mg][r] = 0.f;

    for (int jy = 0; jy < 3; ++jy) {
        if ((unsigned)(row + jy - 1) >= 256u) continue;
        const char* pp = Pt + jy * PPA;
        for (int jx = 0; jx < 3; ++jx) {
            const int j = jy * 3 + jx;
            const float bj = bias9[j];
#pragma unroll
            for (int mg = 0; mg < 4; ++mg)
#pragma unroll
                for (int r = 0; r < 4; ++r) {
                    int tpx = mg * 16 + (q << 2) + r + jx;
                    unsigned short pv = *(const unsigned short*)
                        (pp + tpx * 128 + ((c_lane * 2 + (((tpx - 1) & 7) << 4)) & 127));
                    yv[mg][r] = fmaf(acc[mg][j][r] + bj, bf2f(pv), yv[mg][r]);
                }
        }
    }

    // y -> LDS (bf16, rotated) ; z = y @ dw^T via MFMA
#pragma unroll
    for (int mg = 0; mg < 4; ++mg)
#pragma unroll
        for (int r = 0; r < 4; ++r) {
            int px_t = mg * 16 + (q << 2) + r;
            *(unsigned short*)(Ys + px_t * 128 + ((c_lane * 2 + ((px_t & 7) << 4)) & 127)) = f2bf(yv[mg][r]);
        }
    __syncthreads();

    v4f zacc[4];
#pragma unroll
    for (int mg = 0; mg < 4; ++mg) zacc[mg] = (v4f)(0.f);
#pragma unroll
    for (int kick = 0; kick < 2; ++kick) {
        v8s bf = *(const v8s*)(Dw + (((kick << 2) + w) << 10) + (lane << 4));
#pragma unroll
        for (int mg2 = 0; mg2 < 4; ++mg2) {
            int off = ((kick << 6) + (q << 4) + ((m16 & 7) << 4)) & 127;
            v8s af2 = *(const v8s*)(Ys + (mg2 * 16 + m16) * 128 + off);
            zacc[mg2] = __builtin_amdgcn_mfma_f32_16x16x32_bf16(af2, bf, zacc[mg2], 0, 0, 0);
        }
    }

    // z store + fused BN-stat partials
    const int o = w * 16 + m16;
    float* zp = zout + (((size_t)(b * 64 + o)) << 16) + ((size_t)row << 8);
    float a1 = 0.f, a2 = 0.f;
#pragma unroll
    for (int mg2 = 0; mg2 < 4; ++mg2) {
        float4 vv = make_float4(zacc[mg2][0], zacc[mg2][1], zacc[mg2][2], zacc[mg2][3]);
        a1 += vv.x + vv.y + vv.z + vv.w;
        a2 += vv.x * vv.x + vv.y * vv.y + vv.z * vv.z + vv.w * vv.w;
        *(float4*)(zp + col0 + mg2 * 16 + (q << 2)) = vv;
    }
    a1 += __shfl_xor(a1, 16, 64); a1 += __shfl_xor(a1, 32, 64);
    a2 += __shfl_xor(a2, 16, 64); a2 += __shfl_xor(a2, 32, 64);
    if (lane < 16) { atomicAdd(&s1g[o], a1); atomicAdd(&s2g[o], a2); }
}

// ---------------------------------------------------------------------------
__global__ void bn_kernel(const float* __restrict__ z, const float* __restrict__ s1,
                          const float* __restrict__ s2, const float* __restrict__ gamma,
                          const float* __restrict__ beta, float* __restrict__ outp)
{
    size_t idx = ((size_t)blockIdx.x * 256 + threadIdx.x) * 4;
    int o = (int)((idx >> 16) & 63);
    float mu  = s1[o] * (1.f / 131072.f);
    float var = s2[o] * (1.f / 131072.f) - mu * mu;
    float rs  = rsqrtf(var + 1e-5f);
    float scale = gamma[o] * rs;
    float shift = beta[o] - mu * scale;
    float4 v = *(const float4*)(z + idx);
    v.x = fmaxf(v.x * scale + shift, 0.f);
    v.y = fmaxf(v.y * scale + shift, 0.f);
    v.z = fmaxf(v.z * scale + shift, 0.f);
    v.w = fmaxf(v.w * scale + shift, 0.f);
    *(float4*)(outp + idx) = v;
}

// ---------------------------------------------------------------------------
extern "C" void kernel_launch(void* const* d_in, const int* in_sizes, int n_in,
                              void* d_out, int out_size, void* d_ws, size_t ws_size,
                              hipStream_t stream)
{
    const float* input    = (const float*)d_in[0];
    const float* guidance = (const float*)d_in[1];
    const float* cw_w1    = (const float*)d_in[2];
    const float* cw_b1    = (const float*)d_in[3];
    const float* cw_w2    = (const float*)d_in[4];
    const float* cw_b2    = (const float*)d_in[5];
    const float* dw_w1    = (const float*)d_in[6];
    const float* dw_b1    = (const float*)d_in[7];
    const float* dw_w2    = (const float*)d_in[8];
    const float* dw_b2    = (const float*)d_in[9];
    const float* gamma    = (const float*)d_in[10];
    const float* beta     = (const float*)d_in[11];

    char* ws = (char*)d_ws;
    char*  inN   = ws;                            // 16,777,216
    char*  t1    = ws + 16777216;                 // 16,777,216
    char*  Bp1   = ws + 33554432;                 // 147,456
    char*  Bpdw  = ws + 33701888;                 // 147,456
    char*  Bp2   = ws + 33849344;                 // 663,552
    float* hsum  = (float*)(ws + 34512896);       // 512
    float* s1    = (float*)(ws + 34513408);       // 256
    float* s2    = (float*)(ws + 34513664);       // 256
    char*  dwp   = ws + 34513920;                 // 16,384

    char* X0 = (char*)d_out;   // concat bf16 lives in d_out until conv1 done

    hipMemsetAsync(hsum, 0, 1024, stream);   // hsum + s1 + s2 (contiguous)

    transpose_kernel<<<dim3(1024, 2), 256, 0, stream>>>(input, guidance, X0, inN);
    prepack_all<<<1872, 256, 0, stream>>>(cw_w2, cw_w1, dw_w1, Bp2, Bp1, Bpdw);

    conv1_mfma<<<dim3(4, 128, 2), 256, 0, stream>>>(X0, Bp1, Bpdw, cw_b1, dw_b1, t1, hsum);
    dwfused_kernel<<<32, 256, 0, stream>>>(hsum, dw_w2, dw_b2, dwp);

    conv2yz_kernel<<<dim3(4, 256, 2), 256, 0, stream>>>(t1, inN, Bp2, dwp, cw_b2,
                                                        (float*)d_out, s1, s2);

    bn_kernel<<<8192, 256, 0, stream>>>((const float*)d_out, s1, s2, gamma, beta, (float*)d_out);
}